// Round 9
// baseline (385.805 us; speedup 1.0000x reference)
//
#include <hip/hip_runtime.h>

typedef unsigned short u16;
typedef unsigned int u32;
typedef __bf16 bf16x8 __attribute__((ext_vector_type(8)));
typedef _Float16 f16x8 __attribute__((ext_vector_type(8)));
typedef __fp16 fp16x2 __attribute__((ext_vector_type(2)));
typedef float f32x4 __attribute__((ext_vector_type(4)));

__device__ __forceinline__ u16 f2b(float f) {
  u32 u = __float_as_uint(f);
  return (u16)((u + 0x7FFFu + ((u >> 16) & 1u)) >> 16);
}
__device__ __forceinline__ u16 f2h(float f) {
  union { _Float16 h; u16 u; } c;
  c.h = (_Float16)f;
  return c.u;
}
__device__ __forceinline__ u32 pk2h(float a, float b) {
  union { fp16x2 v; u32 u; } c;
  c.v = __builtin_amdgcn_cvt_pkrtz(a, b);
  return c.u;
}
__device__ __forceinline__ u32 pk2b(float a, float b) {
  return (u32)f2b(a) | ((u32)f2b(b) << 16);
}
__device__ __forceinline__ void gl2lds16(const void* g, void* l) {
  __builtin_amdgcn_global_load_lds((__attribute__((address_space(1))) void*)g,
                                   (__attribute__((address_space(3))) void*)l, 16, 0, 0);
}

// exp2 without the hidden *log2e multiply of __expf
#if defined(__has_builtin)
#if __has_builtin(__builtin_amdgcn_exp2f)
#define EXP2F(x) __builtin_amdgcn_exp2f(x)
#endif
#endif
#ifndef EXP2F
#define EXP2F(x) __expf(0.69314718055994531f * (x))
#endif

// P-tile XOR swizzle: row-frame 128 B, 16B-slot index xored with (row&7).
__device__ __forceinline__ u16* pswz(u16* base, int row, int boff) {
  return (u16*)((char*)base + row * 128 + (boff ^ ((row & 7) << 4)));
}

// XCD-aware (m,n) remap for 512-block GEMM grids (dim3(64,8), x-major linear id).
// (Round-8 A/B: neutral vs linear; kept — harmless and stable.)
__device__ __forceinline__ void xcd_mn(int* m0, int* n0) {
  const int lid = blockIdx.x + (int)gridDim.x * blockIdx.y;  // 0..511
  const int xcd = lid & 7, t = lid >> 3;
  *m0 = (xcd * 8 + (t >> 3)) * 128;
  *n0 = (t & 7) * 128;
}

// ---------- fused fp32 -> bf16 transposed weights (all 6 in one launch) ----------
struct W6 {
  const float* src[6];
  u16* dst[6];
};
__global__ __launch_bounds__(256) void k_wtrans6(W6 p) {
  const float* __restrict__ W = p.src[blockIdx.z];
  u16* __restrict__ Wt = p.dst[blockIdx.z];
  __shared__ float sm[64 * 65];
  const int r0 = blockIdx.y * 64, c0 = blockIdx.x * 64;
  const int tid = threadIdx.x;
#pragma unroll
  for (int i = 0; i < 16; ++i) {
    int idx = i * 256 + tid;
    int r = idx >> 6, c = idx & 63;
    sm[c * 65 + r] = W[(size_t)(r0 + r) * 1024 + c0 + c];
  }
  __syncthreads();
#pragma unroll
  for (int i = 0; i < 16; ++i) {
    int idx = i * 256 + tid;
    int r = idx >> 6, c = idx & 63;
    Wt[(size_t)(c0 + r) * 1024 + r0 + c] = f2b(sm[r * 65 + c]);
  }
}

// ---------- layernorm fp32 -> bf16 ----------
__global__ __launch_bounds__(256) void k_ln(const float* __restrict__ x,
                                            const float* __restrict__ w,
                                            const float* __restrict__ bb,
                                            u16* __restrict__ y) {
  const int row = blockIdx.x;
  const int tid = threadIdx.x;
  const float4 v = ((const float4*)(x + (size_t)row * 1024))[tid];
  float s = v.x + v.y + v.z + v.w;
  float s2 = v.x * v.x + v.y * v.y + v.z * v.z + v.w * v.w;
  for (int o = 32; o > 0; o >>= 1) {
    s += __shfl_down(s, o);
    s2 += __shfl_down(s2, o);
  }
  __shared__ float red[8];
  const int wave = tid >> 6;
  if ((tid & 63) == 0) { red[wave * 2] = s; red[wave * 2 + 1] = s2; }
  __syncthreads();
  s = red[0] + red[2] + red[4] + red[6];
  s2 = red[1] + red[3] + red[5] + red[7];
  const float mu = s * (1.0f / 1024.0f);
  const float var = s2 * (1.0f / 1024.0f) - mu * mu;
  const float rs = rsqrtf(var + 1e-5f);
  const float4 wv = ((const float4*)w)[tid];
  const float4 bv = ((const float4*)bb)[tid];
  u16* yr = y + (size_t)row * 1024 + tid * 4;
  yr[0] = f2b((v.x - mu) * rs * wv.x + bv.x);
  yr[1] = f2b((v.y - mu) * rs * wv.y + bv.y);
  yr[2] = f2b((v.z - mu) * rs * wv.z + bv.z);
  yr[3] = f2b((v.w - mu) * rs * wv.w + bv.w);
}

// ---------- 128x128-tile bf16 MFMA GEMM core, BK=32 double-buffered ----------
// T3-lite (guide "minimum 2-phase" recipe): issue next tile's gl2lds BEFORE the
// ds_read+MFMA of the current tile; single __syncthreads per 32-k step (its
// vmcnt drain now waits on loads that had the whole compute phase to land).
// LDS: 2 buffers x (A 8KB | B 8KB) = 32KB — same footprint as the old BK=64 core.
__device__ __forceinline__ void gemm_core_db32(const u16* __restrict__ Ab,
                                               const u16* __restrict__ Bb,
                                               int lda, int ldb, int K,
                                               u16* sm, f32x4 acc[4][4]) {
  const int tid = threadIdx.x;
  const int wave = tid >> 6;
  const int wr = wave >> 1, wc = wave & 1;
  const int lane = tid & 63;
  const int lc = lane & 15, quad = lane >> 4;
  const int sr = tid >> 2, sk = (tid & 3) << 3;
  const u16* gA = Ab + (size_t)sr * lda + sk;
  const u16* gB = Bb + (size_t)sr * ldb + sk;
  const size_t a64 = (size_t)64 * lda, b64 = (size_t)64 * ldb;
  // buffer p: A at sm + p*8192, B at sm + p*8192 + 4096 (u16 units)
  u16* dA = sm + tid * 8;
  u16* dB = sm + 4096 + tid * 8;
  // prologue: stage 32-k tile 0 into buffer 0
  gl2lds16(gA, dA);
  gl2lds16(gA + a64, dA + 2048);
  gl2lds16(gB, dB);
  gl2lds16(gB + b64, dB + 2048);
  __syncthreads();
  int cur = 0;
  const int nt = K >> 5;
  for (int t = 0; t < nt; ++t) {
    const int nxt = cur ^ 1;
    if (t + 1 < nt) {
      const int ko = (t + 1) << 5;
      gl2lds16(gA + ko, dA + nxt * 8192);
      gl2lds16(gA + a64 + ko, dA + nxt * 8192 + 2048);
      gl2lds16(gB + ko, dB + nxt * 8192);
      gl2lds16(gB + b64 + ko, dB + nxt * 8192 + 2048);
    }
    const u16* smA = sm + cur * 8192;
    const u16* smB = sm + cur * 8192 + 4096;
    bf16x8 af[4], bfr[4];
#pragma unroll
    for (int i = 0; i < 4; ++i) {
      af[i] = *(const bf16x8*)(smA + (wr * 64 + i * 16 + lc) * 32 + quad * 8);
      bfr[i] = *(const bf16x8*)(smB + (wc * 64 + i * 16 + lc) * 32 + quad * 8);
    }
#pragma unroll
    for (int i = 0; i < 4; ++i)
#pragma unroll
      for (int j = 0; j < 4; ++j)
        acc[i][j] = __builtin_amdgcn_mfma_f32_16x16x32_bf16(af[i], bfr[j], acc[i][j], 0, 0, 0);
    __syncthreads();
    cur = nxt;
  }
}

// ---------- merged dual GEMM: one A staging feeds BOTH weight matrices ----------
// C0 = A*B0^T -> row-major bf16 (+ optional fused pre-scaled q2)
// C1 = A*B1^T -> per-batch-transposed f16
// BK=32 double-buffered (2 x 24KB = 48KB LDS), prefetch-before-compute.
__global__ __launch_bounds__(256, 2) void k_gemm_nt2(const u16* __restrict__ A,
                                                     const u16* __restrict__ Bt0,
                                                     const u16* __restrict__ Bt1,
                                                     u16* __restrict__ Cn,
                                                     u16* __restrict__ CtT,
                                                     float* __restrict__ q2out,
                                                     const float* __restrict__ tau) {
  __shared__ u16 smem[24576];  // 48 KB: 2 buffers x (A | B0 | B1, 4096 u16 each)
  int m0, n0;
  xcd_mn(&m0, &n0);
  const int tid = threadIdx.x;
  const int wave = tid >> 6;
  const int wr = wave >> 1, wc = wave & 1;
  const int lane = tid & 63;
  const int lc = lane & 15, quad = lane >> 4;
  f32x4 acc0[4][4], acc1[4][4];
#pragma unroll
  for (int i = 0; i < 4; ++i)
#pragma unroll
    for (int j = 0; j < 4; ++j) {
      acc0[i][j] = (f32x4){0.f, 0.f, 0.f, 0.f};
      acc1[i][j] = (f32x4){0.f, 0.f, 0.f, 0.f};
    }
  const int sr = tid >> 2, sk = (tid & 3) << 3;
  const u16* gA = A + (size_t)(m0 + sr) * 1024 + sk;
  const u16* gB0 = Bt0 + (size_t)(n0 + sr) * 1024 + sk;
  const u16* gB1 = Bt1 + (size_t)(n0 + sr) * 1024 + sk;
  const size_t s64 = (size_t)64 * 1024;
  u16* dA = smem + tid * 8;
  u16* dB0 = smem + 4096 + tid * 8;
  u16* dB1 = smem + 8192 + tid * 8;
  // prologue: stage 32-k tile 0 into buffer 0
  gl2lds16(gA, dA);
  gl2lds16(gA + s64, dA + 2048);
  gl2lds16(gB0, dB0);
  gl2lds16(gB0 + s64, dB0 + 2048);
  gl2lds16(gB1, dB1);
  gl2lds16(gB1 + s64, dB1 + 2048);
  __syncthreads();
  int cur = 0;
  for (int t = 0; t < 32; ++t) {
    const int nxt = cur ^ 1;
    if (t + 1 < 32) {
      const int ko = (t + 1) << 5;
      const int nb = nxt * 12288;
      gl2lds16(gA + ko, dA + nb);
      gl2lds16(gA + s64 + ko, dA + nb + 2048);
      gl2lds16(gB0 + ko, dB0 + nb);
      gl2lds16(gB0 + s64 + ko, dB0 + nb + 2048);
      gl2lds16(gB1 + ko, dB1 + nb);
      gl2lds16(gB1 + s64 + ko, dB1 + nb + 2048);
    }
    const u16* smA = smem + cur * 12288;
    const u16* smB0 = smA + 4096;
    const u16* smB1 = smA + 8192;
    bf16x8 af[4], b0[4], b1[4];
#pragma unroll
    for (int i = 0; i < 4; ++i) {
      af[i] = *(const bf16x8*)(smA + (wr * 64 + i * 16 + lc) * 32 + quad * 8);
      b0[i] = *(const bf16x8*)(smB0 + (wc * 64 + i * 16 + lc) * 32 + quad * 8);
      b1[i] = *(const bf16x8*)(smB1 + (wc * 64 + i * 16 + lc) * 32 + quad * 8);
    }
#pragma unroll
    for (int i = 0; i < 4; ++i)
#pragma unroll
      for (int j = 0; j < 4; ++j) {
        acc0[i][j] = __builtin_amdgcn_mfma_f32_16x16x32_bf16(af[i], b0[j], acc0[i][j], 0, 0, 0);
        acc1[i][j] = __builtin_amdgcn_mfma_f32_16x16x32_bf16(af[i], b1[j], acc1[i][j], 0, 0, 0);
      }
    __syncthreads();
    cur = nxt;
  }
  // ---- epilogue 0: row-major bf16 C0 (+ fused pre-scaled q2) ----
  {
    float sq[4][4];
#pragma unroll
    for (int i = 0; i < 4; ++i)
#pragma unroll
      for (int r = 0; r < 4; ++r) sq[i][r] = 0.f;
#pragma unroll
    for (int i = 0; i < 4; ++i)
#pragma unroll
      for (int j = 0; j < 4; ++j) {
        const int n = n0 + wc * 64 + j * 16 + lc;
#pragma unroll
        for (int r = 0; r < 4; ++r) {
          const int m = m0 + wr * 64 + i * 16 + quad * 4 + r;
          const u16 v = f2b(acc0[i][j][r]);
          Cn[(size_t)m * 1024 + n] = v;
          const float cv = __uint_as_float((u32)v << 16);
          sq[i][r] += cv * cv;
        }
      }
    if (q2out) {
      const int h = (n0 >> 6) + wc;  // head index 0..15
      const float hs = tau[h] * 0.18033688011112042f;  // tau/8 * log2(e)
#pragma unroll
      for (int i = 0; i < 4; ++i)
#pragma unroll
        for (int r = 0; r < 4; ++r) {
          float s = sq[i][r];
          s += __shfl_xor(s, 1);
          s += __shfl_xor(s, 2);
          s += __shfl_xor(s, 4);
          s += __shfl_xor(s, 8);
          if (lc == 0) {
            const int m = m0 + wr * 64 + i * 16 + quad * 4 + r;
            const int b = m >> 10, nrow = m & 1023;
            q2out[((size_t)(b * 16 + h)) * 1024 + nrow] = s * hs;
          }
        }
    }
  }
  // ---- epilogue 1: per-batch-transposed f16 C1 (LDS scratch, 64x136 u16) ----
  {
    const int b = m0 >> 10, mloc = m0 & 1023;
    for (int half = 0; half < 2; ++half) {
      if (wc == half) {
#pragma unroll
        for (int i = 0; i < 4; ++i)
#pragma unroll
          for (int j = 0; j < 4; ++j)
#pragma unroll
            for (int r = 0; r < 4; ++r)
              smem[(j * 16 + lc) * 136 + wr * 64 + i * 16 + quad * 4 + r] = f2h(acc1[i][j][r]);
      }
      __syncthreads();
#pragma unroll
      for (int it = 0; it < 4; ++it) {
        const int rr = it * 16 + (tid >> 4);
        const int c8 = (tid & 15) << 3;
        *(uint4*)&CtT[((size_t)(b * 1024 + n0 + half * 64 + rr)) * 1024 + mloc + c8] =
            *(const uint4*)&smem[rr * 136 + c8];
      }
      __syncthreads();
    }
  }
}

// ---------- GEMM + residual epilogue: out = res + acc*gamma[n] (fp32) ----------
__global__ __launch_bounds__(256) void k_gemm_res(const u16* __restrict__ A,
                                                  const u16* __restrict__ Bt,
                                                  const float* __restrict__ res,
                                                  const float* __restrict__ gamma,
                                                  float* __restrict__ out) {
  __shared__ u16 sm[16384];
  int m0, n0;
  xcd_mn(&m0, &n0);
  f32x4 acc[4][4];
#pragma unroll
  for (int i = 0; i < 4; ++i)
#pragma unroll
    for (int j = 0; j < 4; ++j) acc[i][j] = (f32x4){0.f, 0.f, 0.f, 0.f};
  gemm_core_db32(A + (size_t)m0 * 1024, Bt + (size_t)n0 * 1024, 1024, 1024, 1024, sm, acc);
  const int tid = threadIdx.x, wave = tid >> 6;
  const int wr = wave >> 1, wc = wave & 1;
  const int lc = tid & 15, quad = (tid & 63) >> 4;
#pragma unroll
  for (int i = 0; i < 4; ++i)
#pragma unroll
    for (int j = 0; j < 4; ++j) {
      const int n = n0 + wc * 64 + j * 16 + lc;
      const float g = gamma[n];
#pragma unroll
      for (int r = 0; r < 4; ++r) {
        const size_t idx = (size_t)(m0 + wr * 64 + i * 16 + quad * 4 + r) * 1024 + n;
        out[idx] = res[idx] + acc[i][j][r] * g;
      }
    }
}

// ---------- token attention: 128-row q-tile (v2b — verified 58 µs structure) ----------
__global__ __launch_bounds__(256, 4) void k_attn(const u16* __restrict__ qk,   // bf16
                                                 const u16* __restrict__ vT,   // f16 (B,D,N)
                                                 const float* __restrict__ q2, // pre-scaled tau*0.125*log2e
                                                 const float* __restrict__ tau,
                                                 u16* __restrict__ outp) {
  const int bh = blockIdx.x & 127;
  const int q0 = (blockIdx.x >> 7) * 128;
  const int b = bh >> 4, h = bh & 15;
  __shared__ u16 sK[4096];  // [64 k][64 d] bf16, swizzled chunks (8 KB)
  __shared__ u16 sV[4096];  // [64 d][64 n] f16,  swizzled chunks (8 KB)
  __shared__ u16 sP[8192];  // P [128 q][64 k] f16 XOR-swizzled (16 KB); transient Q tile
  const int tid = threadIdx.x;
  const int wave = tid >> 6;
  const int lane = tid & 63;
  const int lc = lane & 15, quad = lane >> 4;
  const int sw = lc & 7;  // xor swizzle key for fragment reads
  const float c2 = tau[h] * 0.36067376022224085f;  // 2 * (1/8) * log2(e)
  const u16* qkb = qk + (size_t)b * (1024 * 1024) + h * 64;
  const u16* vTb = vT + ((size_t)b * 1024 + h * 64) * 1024;
  const float* q2g = q2 + (size_t)bh * 1024;

  const int r0 = tid >> 3, s8 = tid & 7;
  const int rsw = s8 ^ (r0 & 7);  // (r0+32)&7 == r0&7, so shared by both halves
  const int r1 = r0 + 32;

  // stage Q tile (128 rows x 64 d) into sP (transient, flat [row*64] layout)
#pragma unroll
  for (int i = 0; i < 4; ++i)
    gl2lds16(qkb + (size_t)(q0 + i * 32 + r0) * 1024 + rsw * 8, sP + i * 2048 + tid * 8);

  // kt=0 K/V prefetch into registers (overlaps Q staging)
  uint4 pk0 = *(const uint4*)(qkb + (size_t)r0 * 1024 + s8 * 8);
  uint4 pk1 = *(const uint4*)(qkb + (size_t)r1 * 1024 + s8 * 8);
  uint4 pv0 = *(const uint4*)(vTb + (size_t)r0 * 1024 + s8 * 8);
  uint4 pv1 = *(const uint4*)(vTb + (size_t)r1 * 1024 + s8 * 8);

  __syncthreads();  // Q landed (drains all counters)

  const int qr0 = wave * 32 + lc;
  const int qr1 = wave * 32 + 16 + lc;
  const bf16x8 aq00 = *(const bf16x8*)(sP + (qr0 * 8 + (quad ^ sw)) * 8);
  const bf16x8 aq01 = *(const bf16x8*)(sP + (qr0 * 8 + ((4 + quad) ^ sw)) * 8);
  const bf16x8 aq10 = *(const bf16x8*)(sP + (qr1 * 8 + (quad ^ sw)) * 8);
  const bf16x8 aq11 = *(const bf16x8*)(sP + (qr1 * 8 + ((4 + quad) ^ sw)) * 8);
  const float tq0 = q2g[q0 + qr0];
  const float tq1 = q2g[q0 + qr1];

  // swizzled LDS write slots; final layout identical to pre-swizzled gl2lds
  u16* wK0 = sK + (r0 * 8 + rsw) * 8;
  u16* wK1 = sK + 2048 + (r0 * 8 + rsw) * 8;
  u16* wV0 = sV + (r0 * 8 + rsw) * 8;
  u16* wV1 = sV + 2048 + (r0 * 8 + rsw) * 8;

  f32x4 oacc[2][4];
  f32x4 oS[2];  // row-sum accumulators (ones-MFMA)
#pragma unroll
  for (int g = 0; g < 2; ++g) {
    oS[g] = (f32x4){0.f, 0.f, 0.f, 0.f};
#pragma unroll
    for (int j = 0; j < 4; ++j) oacc[g][j] = (f32x4){0.f, 0.f, 0.f, 0.f};
  }
  f16x8 onev;
#pragma unroll
  for (int i = 0; i < 8; ++i) onev[i] = (_Float16)1.0f;

  for (int kt = 0; kt < 16; ++kt) {
    __syncthreads();  // (A) prev tile fully consumed; prefetch vmcnt drained here
    *(uint4*)wK0 = pk0;
    *(uint4*)wK1 = pk1;
    *(uint4*)wV0 = pv0;
    *(uint4*)wV1 = pv1;
    asm volatile("s_waitcnt lgkmcnt(0)" ::: "memory");
    __builtin_amdgcn_sched_barrier(0);
    __builtin_amdgcn_s_barrier();  // (B) raw barrier: prefetch stays in flight
    __builtin_amdgcn_sched_barrier(0);
    const int kbase = kt * 64;

#pragma unroll
    for (int nb = 0; nb < 4; ++nb) {
      const int krow = nb * 16 + lc;
      const bf16x8 bk0 = *(const bf16x8*)(sK + (krow * 8 + (quad ^ sw)) * 8);
      const bf16x8 bk1 = *(const bf16x8*)(sK + (krow * 8 + ((4 + quad) ^ sw)) * 8);
      f32x4 z0 = (f32x4){0.f, 0.f, 0.f, 0.f};
      f32x4 z1 = (f32x4){0.f, 0.f, 0.f, 0.f};
      __builtin_amdgcn_s_setprio(1);
      z0 = __builtin_amdgcn_mfma_f32_16x16x32_bf16(bk0, aq00, z0, 0, 0, 0);
      z0 = __builtin_amdgcn_mfma_f32_16x16x32_bf16(bk1, aq01, z0, 0, 0, 0);
      z1 = __builtin_amdgcn_mfma_f32_16x16x32_bf16(bk0, aq10, z1, 0, 0, 0);
      z1 = __builtin_amdgcn_mfma_f32_16x16x32_bf16(bk1, aq11, z1, 0, 0, 0);
      __builtin_amdgcn_s_setprio(0);
      const float4 tk4 = *(const float4*)(q2g + kbase + nb * 16 + quad * 4);
      {
        const float e0 = EXP2F(fmaf(z0[0], c2, -(tk4.x + tq0)));
        const float e1 = EXP2F(fmaf(z0[1], c2, -(tk4.y + tq0)));
        const float e2 = EXP2F(fmaf(z0[2], c2, -(tk4.z + tq0)));
        const float e3 = EXP2F(fmaf(z0[3], c2, -(tk4.w + tq0)));
        *(uint2*)pswz(sP, qr0, nb * 32 + quad * 8) = make_uint2(pk2h(e0, e1), pk2h(e2, e3));
      }
      {
        const float e0 = EXP2F(fmaf(z1[0], c2, -(tk4.x + tq1)));
        const float e1 = EXP2F(fmaf(z1[1], c2, -(tk4.y + tq1)));
        const float e2 = EXP2F(fmaf(z1[2], c2, -(tk4.z + tq1)));
        const float e3 = EXP2F(fmaf(z1[3], c2, -(tk4.w + tq1)));
        *(uint2*)pswz(sP, qr1, nb * 32 + quad * 8) = make_uint2(pk2h(e0, e1), pk2h(e2, e3));
      }
    }

    if (kt < 15) {
      pk0 = *(const uint4*)(qkb + (size_t)(kbase + 64 + r0) * 1024 + s8 * 8);
      pk1 = *(const uint4*)(qkb + (size_t)(kbase + 64 + r1) * 1024 + s8 * 8);
      pv0 = *(const uint4*)(vTb + (size_t)r0 * 1024 + kbase + 64 + s8 * 8);
      pv1 = *(const uint4*)(vTb + (size_t)r1 * 1024 + kbase + 64 + s8 * 8);
    }

    const f16x8 ap00 = *(const f16x8*)pswz(sP, qr0, quad * 16);
    const f16x8 ap01 = *(const f16x8*)pswz(sP, qr0, 64 + quad * 16);
    const f16x8 ap10 = *(const f16x8*)pswz(sP, qr1, quad * 16);
    const f16x8 ap11 = *(const f16x8*)pswz(sP, qr1, 64 + quad * 16);
    __builtin_amdgcn_s_setprio(1);
#pragma unroll
    for (int j2 = 0; j2 < 4; ++j2) {
      const int drow = j2 * 16 + lc;
      const f16x8 bv0 = *(const f16x8*)(sV + (drow * 8 + (quad ^ sw)) * 8);
      const f16x8 bv1 = *(const f16x8*)(sV + (drow * 8 + ((4 + quad) ^ sw)) * 8);
      oacc[0][j2] = __builtin_amdgcn_mfma_f32_16x16x32_f16(ap00, bv0, oacc[0][j2], 0, 0, 0);
      oacc[0][j2] = __builtin_amdgcn_mfma_f32_16x16x32_f16(ap01, bv1, oacc[0][j2], 0, 0, 0);
      oacc[1][j2] = __builtin_amdgcn_mfma_f32_16x16x32_f16(ap10, bv0, oacc[1][j2], 0, 0, 0);
      oacc[1][j2] = __builtin_amdgcn_mfma_f32_16x16x32_f16(ap11, bv1, oacc[1][j2], 0, 0, 0);
    }
    oS[0] = __builtin_amdgcn_mfma_f32_16x16x32_f16(ap00, onev, oS[0], 0, 0, 0);
    oS[0] = __builtin_amdgcn_mfma_f32_16x16x32_f16(ap01, onev, oS[0], 0, 0, 0);
    oS[1] = __builtin_amdgcn_mfma_f32_16x16x32_f16(ap10, onev, oS[1], 0, 0, 0);
    oS[1] = __builtin_amdgcn_mfma_f32_16x16x32_f16(ap11, onev, oS[1], 0, 0, 0);
    __builtin_amdgcn_s_setprio(0);
  }

#pragma unroll
  for (int g = 0; g < 2; ++g)
#pragma unroll
    for (int r = 0; r < 4; ++r) {
      const float inv = 1.0f / oS[g][r];
      const int row = wave * 32 + g * 16 + quad * 4 + r;
      u16* o = outp + ((size_t)(b * 1024 + q0 + row)) * 1024 + h * 64;
#pragma unroll
      for (int j2 = 0; j2 < 4; ++j2) o[j2 * 16 + lc] = f2b(oacc[g][j2][r] * inv);
    }
}

// ---------- channel Gram, split-K: grid (4 splits, 64 bc), 256 blocks total ----------
__global__ __launch_bounds__(256) void k_chan_gram(const u16* __restrict__ qkcT,  // f16
                                                   float* __restrict__ pG,
                                                   float* __restrict__ pDiag) {
  const int s = blockIdx.x, bc = blockIdx.y, b = bc >> 3, c = bc & 7;
  __shared__ u16 sX[8192];
  const int tid = threadIdx.x, wave = tid >> 6, lane = tid & 63;
  const int lc = lane & 15, quad = lane >> 4;
  const u16* Xb = qkcT + ((size_t)b * 1024 + c * 128) * 1024 + s * 256;
  f32x4 acc[2][8];
#pragma unroll
  for (int i = 0; i < 2; ++i)
#pragma unroll
    for (int j = 0; j < 8; ++j) acc[i][j] = (f32x4){0.f, 0.f, 0.f, 0.f};
  for (int nt = 0; nt < 256; nt += 64) {
#pragma unroll
    for (int i = 0; i < 4; ++i) {
      const int idx = i * 256 + tid;
      gl2lds16(Xb + (size_t)(idx >> 3) * 1024 + nt + ((idx & 7) << 3), sX + idx * 8);
    }
    __syncthreads();
    f16x8 af[2][2];
#pragma unroll
    for (int i = 0; i < 2; ++i)
#pragma unroll
      for (int ks = 0; ks < 2; ++ks)
        af[i][ks] =
            *(const f16x8*)&sX[((wave * 2 + i) * 16 + lc) * 64 + ks * 32 + quad * 8];
#pragma unroll
    for (int nb = 0; nb < 8; ++nb)
#pragma unroll
      for (int ks = 0; ks < 2; ++ks) {
        const f16x8 bb = *(const f16x8*)&sX[(nb * 16 + lc) * 64 + ks * 32 + quad * 8];
        acc[0][nb] = __builtin_amdgcn_mfma_f32_16x16x32_f16(af[0][ks], bb, acc[0][nb], 0, 0, 0);
        acc[1][nb] = __builtin_amdgcn_mfma_f32_16x16x32_f16(af[1][ks], bb, acc[1][nb], 0, 0, 0);
      }
    __syncthreads();
  }
  float* pgb = pG + (size_t)(bc * 4 + s) * 16384;
#pragma unroll
  for (int i = 0; i < 2; ++i) {
    const int rowb = (wave * 2 + i) * 16 + quad * 4;
#pragma unroll
    for (int nb = 0; nb < 8; ++nb)
#pragma unroll
      for (int r = 0; r < 4; ++r)
        pgb[(size_t)(rowb + r) * 128 + nb * 16 + lc] = acc[i][nb][r];
  }
#pragma unroll
  for (int i = 0; i < 2; ++i) {
    const int nbd = wave * 2 + i;
    if ((lc >> 2) == quad)
      pDiag[(size_t)(bc * 4 + s) * 128 + nbd * 16 + lc] = acc[i][nbd][lc & 3];
  }
}

// ---------- channel softmax: reduce 4 partials + row softmax -> bf16 A ----------
__global__ __launch_bounds__(256) void k_chan_sm(const float* __restrict__ pG,
                                                 const float* __restrict__ pDiag,
                                                 const float* __restrict__ tau,
                                                 u16* __restrict__ Aout) {  // bf16
  const int bc = blockIdx.x, c = bc & 7;
  __shared__ float sq2[128];
  const int tid = threadIdx.x;
  const int r = tid >> 1, half = tid & 1;
  if (tid < 128) {
    float d = 0.f;
#pragma unroll
    for (int s = 0; s < 4; ++s) d += pDiag[(size_t)(bc * 4 + s) * 128 + tid];
    sq2[tid] = d;
  }
  const float* g0 = pG + (size_t)bc * 4 * 16384 + r * 128 + half * 64;
  f32x4 v[16];
#pragma unroll
  for (int j = 0; j < 16; ++j) v[j] = ((const f32x4*)g0)[j];
#pragma unroll
  for (int s = 1; s < 4; ++s) {
    const f32x4* gs = (const f32x4*)(g0 + (size_t)s * 16384);
#pragma unroll
    for (int j = 0; j < 16; ++j) v[j] += gs[j];
  }
  __syncthreads();
  const float scl2 = tau[c] * 0.04508422002778011f;  // (1/sqrt(1024)) * log2(e)
  const float c2 = 2.0f * scl2;
  const float q2r = sq2[r];
  float ps = 0.f;
#pragma unroll
  for (int j = 0; j < 16; ++j) {
#pragma unroll
    for (int k = 0; k < 4; ++k) {
      const float q2c = sq2[half * 64 + j * 4 + k];
      const float e = EXP2F(fmaf(v[j][k], c2, -(q2r + q2c) * scl2));
      v[j][k] = e;
      ps += e;
    }
  }
  ps += __shfl_xor(ps, 1);
  const float inv = 1.f / ps;
  uint4* Ao = (uint4*)(Aout + (size_t)bc * 16384 + (size_t)r * 128 + half * 64);
#pragma unroll
  for (int j = 0; j < 8; ++j) {
    uint4 w;
    w.x = pk2b(v[2 * j][0] * inv, v[2 * j][1] * inv);
    w.y = pk2b(v[2 * j][2] * inv, v[2 * j][3] * inv);
    w.z = pk2b(v[2 * j + 1][0] * inv, v[2 * j + 1][1] * inv);
    w.w = pk2b(v[2 * j + 1][2] * inv, v[2 * j + 1][3] * inv);
    Ao[j] = w;
  }
}

// ---------- channel PV: out[b,n,c*128+d] = sum_d' vc[b,n,c*128+d'] * A[d][d'] ----------
__global__ __launch_bounds__(256) void k_chan_pv(const u16* __restrict__ vc,
                                                 const u16* __restrict__ Ac,
                                                 u16* __restrict__ outp) {
  __shared__ u16 sm[16384];
  const int bc = blockIdx.y, b = bc >> 3, c = bc & 7;
  const int m0 = blockIdx.x * 128;
  f32x4 acc[4][4];
#pragma unroll
  for (int i = 0; i < 4; ++i)
#pragma unroll
    for (int j = 0; j < 4; ++j) acc[i][j] = (f32x4){0.f, 0.f, 0.f, 0.f};
  gemm_core_db32(vc + ((size_t)b * 1024 + m0) * 1024 + c * 128, Ac + (size_t)bc * 16384,
                 1024, 128, 128, sm, acc);
  const int tid = threadIdx.x, wave = tid >> 6;
  const int wr = wave >> 1, wc = wave & 1;
  const int lc = tid & 15, quad = (tid & 63) >> 4;
#pragma unroll
  for (int i = 0; i < 4; ++i)
#pragma unroll
    for (int j = 0; j < 4; ++j)
#pragma unroll
      for (int r = 0; r < 4; ++r)
        outp[((size_t)(b * 1024 + m0 + wr * 64 + i * 16 + quad * 4 + r)) * 1024 + c * 128 +
             wc * 64 + j * 16 + lc] = f2b(acc[i][j][r]);
}

extern "C" void kernel_launch(void* const* d_in, const int* in_sizes, int n_in,
                              void* d_out, int out_size, void* d_ws, size_t ws_size,
                              hipStream_t stream) {
  (void)in_sizes; (void)n_in; (void)out_size; (void)ws_size;
  const float* x = (const float*)d_in[0];
  const float* tau_t = (const float*)d_in[4];
  const float* tau_c = (const float*)d_in[8];
  const float* ln1w = (const float*)d_in[9];
  const float* ln1b = (const float*)d_in[10];
  const float* ln2w = (const float*)d_in[11];
  const float* ln2b = (const float*)d_in[12];
  const float* g1 = (const float*)d_in[13];
  const float* g2 = (const float*)d_in[14];
  float* out = (float*)d_out;

  // workspace carve-up
  char* p = (char*)d_ws;
  u16* wb[6];
  for (int i = 0; i < 6; ++i) wb[i] = (u16*)(p + (size_t)i * (2u << 20));
  u16* bufA = (u16*)(p + (size_t)12 * (1u << 20));       // 16 MB
  u16* bufQ = bufA + (size_t)8 * 1024 * 1024;            // 16 MB
  u16* bufV = bufQ + (size_t)8 * 1024 * 1024;            // 16 MB
  float* q2b = (float*)(bufV + (size_t)8 * 1024 * 1024); // 512 KB
  u16* Ac = (u16*)(q2b + 131072 + 8192);                 // 2 MB

  W6 w6;
  const int widx[6] = {1, 2, 3, 5, 6, 7};  // Wqk_t, Wv_t, Wo_t, Wqk_c, Wv_c, Wo_c
  for (int i = 0; i < 6; ++i) { w6.src[i] = (const float*)d_in[widx[i]]; w6.dst[i] = wb[i]; }
  k_wtrans6<<<dim3(16, 16, 6), 256, 0, stream>>>(w6);

  // ---- token diffusion ----
  k_ln<<<8192, 256, 0, stream>>>(x, ln1w, ln1b, bufA);                           // y1 (bf16)
  k_gemm_nt2<<<dim3(64, 8), 256, 0, stream>>>(bufA, wb[0], wb[1], bufQ, bufV, q2b, tau_t);
  k_attn<<<1024, 256, 0, stream>>>(bufQ, bufV, q2b, tau_t, bufA);                // attn_out bf16
  k_gemm_res<<<dim3(64, 8), 256, 0, stream>>>(bufA, wb[2], x, g1, out);          // x1 = x + Wo*g1

  // ---- channel diffusion ----
  k_ln<<<8192, 256, 0, stream>>>(out, ln2w, ln2b, bufQ);                         // y2 (bf16)
  k_gemm_nt2<<<dim3(64, 8), 256, 0, stream>>>(bufQ, wb[4], wb[3], bufA, bufV, nullptr, tau_c);
  // y2 (bufQ) and token q2 (q2b) are dead now: reuse as split-K scratch.
  float* pG = (float*)bufQ;   // 64*4*16384 f32 = 16 MB (exactly bufQ)
  float* pDiag = q2b;         // 64*4*128 f32 = 128 KB
  k_chan_gram<<<dim3(4, 64), 256, 0, stream>>>(bufV, pG, pDiag);                 // partial Grams
  k_chan_sm<<<64, 256, 0, stream>>>(pG, pDiag, tau_c, Ac);                       // reduce+softmax
  k_chan_pv<<<dim3(8, 64), 256, 0, stream>>>(bufA, Ac, bufQ);                    // chan attn out bf16
  k_gemm_res<<<dim3(64, 8), 256, 0, stream>>>(bufQ, wb[5], out, g2, out);        // out = x1 + Wo*g2
}

// Round 10
// 356.248 us; speedup vs baseline: 1.0830x; 1.0830x over previous
//
#include <hip/hip_runtime.h>

typedef unsigned short u16;
typedef unsigned int u32;
typedef __bf16 bf16x8 __attribute__((ext_vector_type(8)));
typedef _Float16 f16x8 __attribute__((ext_vector_type(8)));
typedef __fp16 fp16x2 __attribute__((ext_vector_type(2)));
typedef float f32x4 __attribute__((ext_vector_type(4)));

__device__ __forceinline__ u16 f2b(float f) {
  u32 u = __float_as_uint(f);
  return (u16)((u + 0x7FFFu + ((u >> 16) & 1u)) >> 16);
}
__device__ __forceinline__ u16 f2h(float f) {
  union { _Float16 h; u16 u; } c;
  c.h = (_Float16)f;
  return c.u;
}
__device__ __forceinline__ u32 pk2h(float a, float b) {
  union { fp16x2 v; u32 u; } c;
  c.v = __builtin_amdgcn_cvt_pkrtz(a, b);
  return c.u;
}
__device__ __forceinline__ u32 pk2b(float a, float b) {
  return (u32)f2b(a) | ((u32)f2b(b) << 16);
}
__device__ __forceinline__ void gl2lds16(const void* g, void* l) {
  __builtin_amdgcn_global_load_lds((__attribute__((address_space(1))) void*)g,
                                   (__attribute__((address_space(3))) void*)l, 16, 0, 0);
}

// exp2 without the hidden *log2e multiply of __expf
#if defined(__has_builtin)
#if __has_builtin(__builtin_amdgcn_exp2f)
#define EXP2F(x) __builtin_amdgcn_exp2f(x)
#endif
#endif
#ifndef EXP2F
#define EXP2F(x) __expf(0.69314718055994531f * (x))
#endif

// P-tile XOR swizzle: row-frame 128 B, 16B-slot index xored with (row&7).
__device__ __forceinline__ u16* pswz(u16* base, int row, int boff) {
  return (u16*)((char*)base + row * 128 + (boff ^ ((row & 7) << 4)));
}

// ---------- fused fp32 -> bf16 transposed weights (all 6 in one launch) ----------
struct W6 {
  const float* src[6];
  u16* dst[6];
};
__global__ __launch_bounds__(256) void k_wtrans6(W6 p) {
  const float* __restrict__ W = p.src[blockIdx.z];
  u16* __restrict__ Wt = p.dst[blockIdx.z];
  __shared__ float sm[64 * 65];
  const int r0 = blockIdx.y * 64, c0 = blockIdx.x * 64;
  const int tid = threadIdx.x;
#pragma unroll
  for (int i = 0; i < 16; ++i) {
    int idx = i * 256 + tid;
    int r = idx >> 6, c = idx & 63;
    sm[c * 65 + r] = W[(size_t)(r0 + r) * 1024 + c0 + c];
  }
  __syncthreads();
#pragma unroll
  for (int i = 0; i < 16; ++i) {
    int idx = i * 256 + tid;
    int r = idx >> 6, c = idx & 63;
    Wt[(size_t)(c0 + r) * 1024 + r0 + c] = f2b(sm[r * 65 + c]);
  }
}

// ---------- layernorm fp32 -> bf16 ----------
__global__ __launch_bounds__(256) void k_ln(const float* __restrict__ x,
                                            const float* __restrict__ w,
                                            const float* __restrict__ bb,
                                            u16* __restrict__ y) {
  const int row = blockIdx.x;
  const int tid = threadIdx.x;
  const float4 v = ((const float4*)(x + (size_t)row * 1024))[tid];
  float s = v.x + v.y + v.z + v.w;
  float s2 = v.x * v.x + v.y * v.y + v.z * v.z + v.w * v.w;
  for (int o = 32; o > 0; o >>= 1) {
    s += __shfl_down(s, o);
    s2 += __shfl_down(s2, o);
  }
  __shared__ float red[8];
  const int wave = tid >> 6;
  if ((tid & 63) == 0) { red[wave * 2] = s; red[wave * 2 + 1] = s2; }
  __syncthreads();
  s = red[0] + red[2] + red[4] + red[6];
  s2 = red[1] + red[3] + red[5] + red[7];
  const float mu = s * (1.0f / 1024.0f);
  const float var = s2 * (1.0f / 1024.0f) - mu * mu;
  const float rs = rsqrtf(var + 1e-5f);
  const float4 wv = ((const float4*)w)[tid];
  const float4 bv = ((const float4*)bb)[tid];
  u16* yr = y + (size_t)row * 1024 + tid * 4;
  yr[0] = f2b((v.x - mu) * rs * wv.x + bv.x);
  yr[1] = f2b((v.y - mu) * rs * wv.y + bv.y);
  yr[2] = f2b((v.z - mu) * rs * wv.z + bv.z);
  yr[3] = f2b((v.w - mu) * rs * wv.w + bv.w);
}

// ---------- 128x128-tile bf16 MFMA GEMM core, BK=64 (two 32-k sub-tiles/barrier) ----------
// NOTE (r9 lesson): BK=32 explicit double-buffer REGRESSED (−7%): halving
// MFMA-per-barrier doubles the vmcnt(0)+barrier drains, which dominate this
// skeleton. Keep 32 MFMA per barrier-pair.
__device__ __forceinline__ void gemm_core_bk64(const u16* __restrict__ Ab,
                                               const u16* __restrict__ Bb,
                                               int lda, int ldb, int K,
                                               u16* sm, f32x4 acc[4][4]) {
  const int tid = threadIdx.x;
  const int wave = tid >> 6;
  const int wr = wave >> 1, wc = wave & 1;
  const int lane = tid & 63;
  const int lc = lane & 15, quad = lane >> 4;
  u16* smA = sm;
  u16* smB = sm + 8192;
  const int sr = tid >> 2, sk = (tid & 3) << 3;
  const u16* gA = Ab + (size_t)sr * lda + sk;
  const u16* gB = Bb + (size_t)sr * ldb + sk;
  const size_t a64 = (size_t)64 * lda, b64 = (size_t)64 * ldb;
  u16* dA = smA + tid * 8;
  u16* dB = smB + tid * 8;
  for (int kt = 0; kt < K; kt += 64) {
    gl2lds16(gA + kt, dA);
    gl2lds16(gA + a64 + kt, dA + 2048);
    gl2lds16(gB + kt, dB);
    gl2lds16(gB + b64 + kt, dB + 2048);
    gl2lds16(gA + kt + 32, dA + 4096);
    gl2lds16(gA + a64 + kt + 32, dA + 6144);
    gl2lds16(gB + kt + 32, dB + 4096);
    gl2lds16(gB + b64 + kt + 32, dB + 6144);
    __syncthreads();
#pragma unroll
    for (int ks = 0; ks < 2; ++ks) {
      bf16x8 af[4], bfr[4];
#pragma unroll
      for (int i = 0; i < 4; ++i) {
        af[i] = *(const bf16x8*)(smA + ks * 4096 + (wr * 64 + i * 16 + lc) * 32 + quad * 8);
        bfr[i] = *(const bf16x8*)(smB + ks * 4096 + (wc * 64 + i * 16 + lc) * 32 + quad * 8);
      }
#pragma unroll
      for (int i = 0; i < 4; ++i)
#pragma unroll
        for (int j = 0; j < 4; ++j)
          acc[i][j] = __builtin_amdgcn_mfma_f32_16x16x32_bf16(af[i], bfr[j], acc[i][j], 0, 0, 0);
    }
    __syncthreads();
  }
}

// ---------- merged dual GEMM: one A staging feeds BOTH weight matrices ----------
// C0 = A*B0^T -> row-major bf16 (+ optional fused pre-scaled q2)
// C1 = A*B1^T -> per-batch-transposed f16
// 48KB LDS (A|B0|B1), 64 MFMA per barrier-pair, A read once.
__global__ __launch_bounds__(256, 2) void k_gemm_nt2(const u16* __restrict__ A,
                                                     const u16* __restrict__ Bt0,
                                                     const u16* __restrict__ Bt1,
                                                     u16* __restrict__ Cn,
                                                     u16* __restrict__ CtT,
                                                     float* __restrict__ q2out,
                                                     const float* __restrict__ tau) {
  __shared__ u16 smem[24576];  // 48 KB: A | B0 | B1 (8192 u16 each)
  u16* smA = smem;
  u16* smB0 = smem + 8192;
  u16* smB1 = smem + 16384;
  const int m0 = blockIdx.x * 128, n0 = blockIdx.y * 128;
  const int tid = threadIdx.x;
  const int wave = tid >> 6;
  const int wr = wave >> 1, wc = wave & 1;
  const int lane = tid & 63;
  const int lc = lane & 15, quad = lane >> 4;
  f32x4 acc0[4][4], acc1[4][4];
#pragma unroll
  for (int i = 0; i < 4; ++i)
#pragma unroll
    for (int j = 0; j < 4; ++j) {
      acc0[i][j] = (f32x4){0.f, 0.f, 0.f, 0.f};
      acc1[i][j] = (f32x4){0.f, 0.f, 0.f, 0.f};
    }
  const int sr = tid >> 2, sk = (tid & 3) << 3;
  const u16* gA = A + (size_t)(m0 + sr) * 1024 + sk;
  const u16* gB0 = Bt0 + (size_t)(n0 + sr) * 1024 + sk;
  const u16* gB1 = Bt1 + (size_t)(n0 + sr) * 1024 + sk;
  const size_t s64 = (size_t)64 * 1024;
  u16* dA = smA + tid * 8;
  u16* dB0 = smB0 + tid * 8;
  u16* dB1 = smB1 + tid * 8;
  for (int kt = 0; kt < 1024; kt += 64) {
    gl2lds16(gA + kt, dA);
    gl2lds16(gA + s64 + kt, dA + 2048);
    gl2lds16(gA + kt + 32, dA + 4096);
    gl2lds16(gA + s64 + kt + 32, dA + 6144);
    gl2lds16(gB0 + kt, dB0);
    gl2lds16(gB0 + s64 + kt, dB0 + 2048);
    gl2lds16(gB0 + kt + 32, dB0 + 4096);
    gl2lds16(gB0 + s64 + kt + 32, dB0 + 6144);
    gl2lds16(gB1 + kt, dB1);
    gl2lds16(gB1 + s64 + kt, dB1 + 2048);
    gl2lds16(gB1 + kt + 32, dB1 + 4096);
    gl2lds16(gB1 + s64 + kt + 32, dB1 + 6144);
    __syncthreads();
#pragma unroll
    for (int ks = 0; ks < 2; ++ks) {
      bf16x8 af[4], b0[4], b1[4];
#pragma unroll
      for (int i = 0; i < 4; ++i) {
        af[i] = *(const bf16x8*)(smA + ks * 4096 + (wr * 64 + i * 16 + lc) * 32 + quad * 8);
        b0[i] = *(const bf16x8*)(smB0 + ks * 4096 + (wc * 64 + i * 16 + lc) * 32 + quad * 8);
        b1[i] = *(const bf16x8*)(smB1 + ks * 4096 + (wc * 64 + i * 16 + lc) * 32 + quad * 8);
      }
#pragma unroll
      for (int i = 0; i < 4; ++i)
#pragma unroll
        for (int j = 0; j < 4; ++j) {
          acc0[i][j] = __builtin_amdgcn_mfma_f32_16x16x32_bf16(af[i], b0[j], acc0[i][j], 0, 0, 0);
          acc1[i][j] = __builtin_amdgcn_mfma_f32_16x16x32_bf16(af[i], b1[j], acc1[i][j], 0, 0, 0);
        }
    }
    __syncthreads();
  }
  // ---- epilogue 0: row-major bf16 C0 (+ fused pre-scaled q2) ----
  {
    float sq[4][4];
#pragma unroll
    for (int i = 0; i < 4; ++i)
#pragma unroll
      for (int r = 0; r < 4; ++r) sq[i][r] = 0.f;
#pragma unroll
    for (int i = 0; i < 4; ++i)
#pragma unroll
      for (int j = 0; j < 4; ++j) {
        const int n = n0 + wc * 64 + j * 16 + lc;
#pragma unroll
        for (int r = 0; r < 4; ++r) {
          const int m = m0 + wr * 64 + i * 16 + quad * 4 + r;
          const u16 v = f2b(acc0[i][j][r]);
          Cn[(size_t)m * 1024 + n] = v;
          const float cv = __uint_as_float((u32)v << 16);
          sq[i][r] += cv * cv;
        }
      }
    if (q2out) {
      const int h = (n0 >> 6) + wc;  // head index 0..15
      const float hs = tau[h] * 0.18033688011112042f;  // tau/8 * log2(e)
#pragma unroll
      for (int i = 0; i < 4; ++i)
#pragma unroll
        for (int r = 0; r < 4; ++r) {
          float s = sq[i][r];
          s += __shfl_xor(s, 1);
          s += __shfl_xor(s, 2);
          s += __shfl_xor(s, 4);
          s += __shfl_xor(s, 8);
          if (lc == 0) {
            const int m = m0 + wr * 64 + i * 16 + quad * 4 + r;
            const int b = m >> 10, nrow = m & 1023;
            q2out[((size_t)(b * 16 + h)) * 1024 + nrow] = s * hs;
          }
        }
    }
  }
  // ---- epilogue 1: per-batch-transposed f16 C1 (LDS scratch, 64x136 u16) ----
  {
    const int b = m0 >> 10, mloc = m0 & 1023;
    for (int half = 0; half < 2; ++half) {
      if (wc == half) {
#pragma unroll
        for (int i = 0; i < 4; ++i)
#pragma unroll
          for (int j = 0; j < 4; ++j)
#pragma unroll
            for (int r = 0; r < 4; ++r)
              smem[(j * 16 + lc) * 136 + wr * 64 + i * 16 + quad * 4 + r] = f2h(acc1[i][j][r]);
      }
      __syncthreads();
#pragma unroll
      for (int it = 0; it < 4; ++it) {
        const int rr = it * 16 + (tid >> 4);
        const int c8 = (tid & 15) << 3;
        *(uint4*)&CtT[((size_t)(b * 1024 + n0 + half * 64 + rr)) * 1024 + mloc + c8] =
            *(const uint4*)&smem[rr * 136 + c8];
      }
      __syncthreads();
    }
  }
}

// ---------- GEMM + residual epilogue: out = res + acc*gamma[n] (fp32) ----------
__global__ __launch_bounds__(256) void k_gemm_res(const u16* __restrict__ A,
                                                  const u16* __restrict__ Bt,
                                                  const float* __restrict__ res,
                                                  const float* __restrict__ gamma,
                                                  float* __restrict__ out) {
  __shared__ u16 sm[16384];
  const int m0 = blockIdx.x * 128, n0 = blockIdx.y * 128;
  f32x4 acc[4][4];
#pragma unroll
  for (int i = 0; i < 4; ++i)
#pragma unroll
    for (int j = 0; j < 4; ++j) acc[i][j] = (f32x4){0.f, 0.f, 0.f, 0.f};
  gemm_core_bk64(A + (size_t)m0 * 1024, Bt + (size_t)n0 * 1024, 1024, 1024, 1024, sm, acc);
  const int tid = threadIdx.x, wave = tid >> 6;
  const int wr = wave >> 1, wc = wave & 1;
  const int lc = tid & 15, quad = (tid & 63) >> 4;
#pragma unroll
  for (int i = 0; i < 4; ++i)
#pragma unroll
    for (int j = 0; j < 4; ++j) {
      const int n = n0 + wc * 64 + j * 16 + lc;
      const float g = gamma[n];
#pragma unroll
      for (int r = 0; r < 4; ++r) {
        const size_t idx = (size_t)(m0 + wr * 64 + i * 16 + quad * 4 + r) * 1024 + n;
        out[idx] = res[idx] + acc[i][j][r] * g;
      }
    }
}

// ---------- token attention: 128-row q-tile (v2b — verified 58 µs structure) ----------
__global__ __launch_bounds__(256, 4) void k_attn(const u16* __restrict__ qk,   // bf16
                                                 const u16* __restrict__ vT,   // f16 (B,D,N)
                                                 const float* __restrict__ q2, // pre-scaled tau*0.125*log2e
                                                 const float* __restrict__ tau,
                                                 u16* __restrict__ outp) {
  const int bh = blockIdx.x & 127;
  const int q0 = (blockIdx.x >> 7) * 128;
  const int b = bh >> 4, h = bh & 15;
  __shared__ u16 sK[4096];  // [64 k][64 d] bf16, swizzled chunks (8 KB)
  __shared__ u16 sV[4096];  // [64 d][64 n] f16,  swizzled chunks (8 KB)
  __shared__ u16 sP[8192];  // P [128 q][64 k] f16 XOR-swizzled (16 KB); transient Q tile
  const int tid = threadIdx.x;
  const int wave = tid >> 6;
  const int lane = tid & 63;
  const int lc = lane & 15, quad = lane >> 4;
  const int sw = lc & 7;  // xor swizzle key for fragment reads
  const float c2 = tau[h] * 0.36067376022224085f;  // 2 * (1/8) * log2(e)
  const u16* qkb = qk + (size_t)b * (1024 * 1024) + h * 64;
  const u16* vTb = vT + ((size_t)b * 1024 + h * 64) * 1024;
  const float* q2g = q2 + (size_t)bh * 1024;

  const int r0 = tid >> 3, s8 = tid & 7;
  const int rsw = s8 ^ (r0 & 7);  // (r0+32)&7 == r0&7, so shared by both halves
  const int r1 = r0 + 32;

  // stage Q tile (128 rows x 64 d) into sP (transient, flat [row*64] layout)
#pragma unroll
  for (int i = 0; i < 4; ++i)
    gl2lds16(qkb + (size_t)(q0 + i * 32 + r0) * 1024 + rsw * 8, sP + i * 2048 + tid * 8);

  // kt=0 K/V prefetch into registers (overlaps Q staging)
  uint4 pk0 = *(const uint4*)(qkb + (size_t)r0 * 1024 + s8 * 8);
  uint4 pk1 = *(const uint4*)(qkb + (size_t)r1 * 1024 + s8 * 8);
  uint4 pv0 = *(const uint4*)(vTb + (size_t)r0 * 1024 + s8 * 8);
  uint4 pv1 = *(const uint4*)(vTb + (size_t)r1 * 1024 + s8 * 8);

  __syncthreads();  // Q landed (drains all counters)

  const int qr0 = wave * 32 + lc;
  const int qr1 = wave * 32 + 16 + lc;
  const bf16x8 aq00 = *(const bf16x8*)(sP + (qr0 * 8 + (quad ^ sw)) * 8);
  const bf16x8 aq01 = *(const bf16x8*)(sP + (qr0 * 8 + ((4 + quad) ^ sw)) * 8);
  const bf16x8 aq10 = *(const bf16x8*)(sP + (qr1 * 8 + (quad ^ sw)) * 8);
  const bf16x8 aq11 = *(const bf16x8*)(sP + (qr1 * 8 + ((4 + quad) ^ sw)) * 8);
  const float tq0 = q2g[q0 + qr0];
  const float tq1 = q2g[q0 + qr1];

  // swizzled LDS write slots; final layout identical to pre-swizzled gl2lds
  u16* wK0 = sK + (r0 * 8 + rsw) * 8;
  u16* wK1 = sK + 2048 + (r0 * 8 + rsw) * 8;
  u16* wV0 = sV + (r0 * 8 + rsw) * 8;
  u16* wV1 = sV + 2048 + (r0 * 8 + rsw) * 8;

  f32x4 oacc[2][4];
  f32x4 oS[2];  // row-sum accumulators (ones-MFMA)
#pragma unroll
  for (int g = 0; g < 2; ++g) {
    oS[g] = (f32x4){0.f, 0.f, 0.f, 0.f};
#pragma unroll
    for (int j = 0; j < 4; ++j) oacc[g][j] = (f32x4){0.f, 0.f, 0.f, 0.f};
  }
  f16x8 onev;
#pragma unroll
  for (int i = 0; i < 8; ++i) onev[i] = (_Float16)1.0f;

  for (int kt = 0; kt < 16; ++kt) {
    __syncthreads();  // (A) prev tile fully consumed; prefetch vmcnt drained here
    *(uint4*)wK0 = pk0;
    *(uint4*)wK1 = pk1;
    *(uint4*)wV0 = pv0;
    *(uint4*)wV1 = pv1;
    asm volatile("s_waitcnt lgkmcnt(0)" ::: "memory");
    __builtin_amdgcn_sched_barrier(0);
    __builtin_amdgcn_s_barrier();  // (B) raw barrier: prefetch stays in flight
    __builtin_amdgcn_sched_barrier(0);
    const int kbase = kt * 64;

#pragma unroll
    for (int nb = 0; nb < 4; ++nb) {
      const int krow = nb * 16 + lc;
      const bf16x8 bk0 = *(const bf16x8*)(sK + (krow * 8 + (quad ^ sw)) * 8);
      const bf16x8 bk1 = *(const bf16x8*)(sK + (krow * 8 + ((4 + quad) ^ sw)) * 8);
      f32x4 z0 = (f32x4){0.f, 0.f, 0.f, 0.f};
      f32x4 z1 = (f32x4){0.f, 0.f, 0.f, 0.f};
      __builtin_amdgcn_s_setprio(1);
      z0 = __builtin_amdgcn_mfma_f32_16x16x32_bf16(bk0, aq00, z0, 0, 0, 0);
      z0 = __builtin_amdgcn_mfma_f32_16x16x32_bf16(bk1, aq01, z0, 0, 0, 0);
      z1 = __builtin_amdgcn_mfma_f32_16x16x32_bf16(bk0, aq10, z1, 0, 0, 0);
      z1 = __builtin_amdgcn_mfma_f32_16x16x32_bf16(bk1, aq11, z1, 0, 0, 0);
      __builtin_amdgcn_s_setprio(0);
      const float4 tk4 = *(const float4*)(q2g + kbase + nb * 16 + quad * 4);
      {
        const float e0 = EXP2F(fmaf(z0[0], c2, -(tk4.x + tq0)));
        const float e1 = EXP2F(fmaf(z0[1], c2, -(tk4.y + tq0)));
        const float e2 = EXP2F(fmaf(z0[2], c2, -(tk4.z + tq0)));
        const float e3 = EXP2F(fmaf(z0[3], c2, -(tk4.w + tq0)));
        *(uint2*)pswz(sP, qr0, nb * 32 + quad * 8) = make_uint2(pk2h(e0, e1), pk2h(e2, e3));
      }
      {
        const float e0 = EXP2F(fmaf(z1[0], c2, -(tk4.x + tq1)));
        const float e1 = EXP2F(fmaf(z1[1], c2, -(tk4.y + tq1)));
        const float e2 = EXP2F(fmaf(z1[2], c2, -(tk4.z + tq1)));
        const float e3 = EXP2F(fmaf(z1[3], c2, -(tk4.w + tq1)));
        *(uint2*)pswz(sP, qr1, nb * 32 + quad * 8) = make_uint2(pk2h(e0, e1), pk2h(e2, e3));
      }
    }

    if (kt < 15) {
      pk0 = *(const uint4*)(qkb + (size_t)(kbase + 64 + r0) * 1024 + s8 * 8);
      pk1 = *(const uint4*)(qkb + (size_t)(kbase + 64 + r1) * 1024 + s8 * 8);
      pv0 = *(const uint4*)(vTb + (size_t)r0 * 1024 + kbase + 64 + s8 * 8);
      pv1 = *(const uint4*)(vTb + (size_t)r1 * 1024 + kbase + 64 + s8 * 8);
    }

    const f16x8 ap00 = *(const f16x8*)pswz(sP, qr0, quad * 16);
    const f16x8 ap01 = *(const f16x8*)pswz(sP, qr0, 64 + quad * 16);
    const f16x8 ap10 = *(const f16x8*)pswz(sP, qr1, quad * 16);
    const f16x8 ap11 = *(const f16x8*)pswz(sP, qr1, 64 + quad * 16);
    __builtin_amdgcn_s_setprio(1);
#pragma unroll
    for (int j2 = 0; j2 < 4; ++j2) {
      const int drow = j2 * 16 + lc;
      const f16x8 bv0 = *(const f16x8*)(sV + (drow * 8 + (quad ^ sw)) * 8);
      const f16x8 bv1 = *(const f16x8*)(sV + (drow * 8 + ((4 + quad) ^ sw)) * 8);
      oacc[0][j2] = __builtin_amdgcn_mfma_f32_16x16x32_f16(ap00, bv0, oacc[0][j2], 0, 0, 0);
      oacc[0][j2] = __builtin_amdgcn_mfma_f32_16x16x32_f16(ap01, bv1, oacc[0][j2], 0, 0, 0);
      oacc[1][j2] = __builtin_amdgcn_mfma_f32_16x16x32_f16(ap10, bv0, oacc[1][j2], 0, 0, 0);
      oacc[1][j2] = __builtin_amdgcn_mfma_f32_16x16x32_f16(ap11, bv1, oacc[1][j2], 0, 0, 0);
    }
    oS[0] = __builtin_amdgcn_mfma_f32_16x16x32_f16(ap00, onev, oS[0], 0, 0, 0);
    oS[0] = __builtin_amdgcn_mfma_f32_16x16x32_f16(ap01, onev, oS[0], 0, 0, 0);
    oS[1] = __builtin_amdgcn_mfma_f32_16x16x32_f16(ap10, onev, oS[1], 0, 0, 0);
    oS[1] = __builtin_amdgcn_mfma_f32_16x16x32_f16(ap11, onev, oS[1], 0, 0, 0);
    __builtin_amdgcn_s_setprio(0);
  }

#pragma unroll
  for (int g = 0; g < 2; ++g)
#pragma unroll
    for (int r = 0; r < 4; ++r) {
      const float inv = 1.0f / oS[g][r];
      const int row = wave * 32 + g * 16 + quad * 4 + r;
      u16* o = outp + ((size_t)(b * 1024 + q0 + row)) * 1024 + h * 64;
#pragma unroll
      for (int j2 = 0; j2 < 4; ++j2) o[j2 * 16 + lc] = f2b(oacc[g][j2][r] * inv);
    }
}

// ---------- channel Gram, split-K: grid (4 splits, 64 bc), 256 blocks total ----------
__global__ __launch_bounds__(256) void k_chan_gram(const u16* __restrict__ qkcT,  // f16
                                                   float* __restrict__ pG,
                                                   float* __restrict__ pDiag) {
  const int s = blockIdx.x, bc = blockIdx.y, b = bc >> 3, c = bc & 7;
  __shared__ u16 sX[8192];
  const int tid = threadIdx.x, wave = tid >> 6, lane = tid & 63;
  const int lc = lane & 15, quad = lane >> 4;
  const u16* Xb = qkcT + ((size_t)b * 1024 + c * 128) * 1024 + s * 256;
  f32x4 acc[2][8];
#pragma unroll
  for (int i = 0; i < 2; ++i)
#pragma unroll
    for (int j = 0; j < 8; ++j) acc[i][j] = (f32x4){0.f, 0.f, 0.f, 0.f};
  for (int nt = 0; nt < 256; nt += 64) {
#pragma unroll
    for (int i = 0; i < 4; ++i) {
      const int idx = i * 256 + tid;
      gl2lds16(Xb + (size_t)(idx >> 3) * 1024 + nt + ((idx & 7) << 3), sX + idx * 8);
    }
    __syncthreads();
    f16x8 af[2][2];
#pragma unroll
    for (int i = 0; i < 2; ++i)
#pragma unroll
      for (int ks = 0; ks < 2; ++ks)
        af[i][ks] =
            *(const f16x8*)&sX[((wave * 2 + i) * 16 + lc) * 64 + ks * 32 + quad * 8];
#pragma unroll
    for (int nb = 0; nb < 8; ++nb)
#pragma unroll
      for (int ks = 0; ks < 2; ++ks) {
        const f16x8 bb = *(const f16x8*)&sX[(nb * 16 + lc) * 64 + ks * 32 + quad * 8];
        acc[0][nb] = __builtin_amdgcn_mfma_f32_16x16x32_f16(af[0][ks], bb, acc[0][nb], 0, 0, 0);
        acc[1][nb] = __builtin_amdgcn_mfma_f32_16x16x32_f16(af[1][ks], bb, acc[1][nb], 0, 0, 0);
      }
    __syncthreads();
  }
  float* pgb = pG + (size_t)(bc * 4 + s) * 16384;
#pragma unroll
  for (int i = 0; i < 2; ++i) {
    const int rowb = (wave * 2 + i) * 16 + quad * 4;
#pragma unroll
    for (int nb = 0; nb < 8; ++nb)
#pragma unroll
      for (int r = 0; r < 4; ++r)
        pgb[(size_t)(rowb + r) * 128 + nb * 16 + lc] = acc[i][nb][r];
  }
#pragma unroll
  for (int i = 0; i < 2; ++i) {
    const int nbd = wave * 2 + i;
    if ((lc >> 2) == quad)
      pDiag[(size_t)(bc * 4 + s) * 128 + nbd * 16 + lc] = acc[i][nbd][lc & 3];
  }
}

// ---------- channel softmax: reduce 4 partials + row softmax -> bf16 A ----------
__global__ __launch_bounds__(256) void k_chan_sm(const float* __restrict__ pG,
                                                 const float* __restrict__ pDiag,
                                                 const float* __restrict__ tau,
                                                 u16* __restrict__ Aout) {  // bf16
  const int bc = blockIdx.x, c = bc & 7;
  __shared__ float sq2[128];
  const int tid = threadIdx.x;
  const int r = tid >> 1, half = tid & 1;
  if (tid < 128) {
    float d = 0.f;
#pragma unroll
    for (int s = 0; s < 4; ++s) d += pDiag[(size_t)(bc * 4 + s) * 128 + tid];
    sq2[tid] = d;
  }
  const float* g0 = pG + (size_t)bc * 4 * 16384 + r * 128 + half * 64;
  f32x4 v[16];
#pragma unroll
  for (int j = 0; j < 16; ++j) v[j] = ((const f32x4*)g0)[j];
#pragma unroll
  for (int s = 1; s < 4; ++s) {
    const f32x4* gs = (const f32x4*)(g0 + (size_t)s * 16384);
#pragma unroll
    for (int j = 0; j < 16; ++j) v[j] += gs[j];
  }
  __syncthreads();
  const float scl2 = tau[c] * 0.04508422002778011f;  // (1/sqrt(1024)) * log2(e)
  const float c2 = 2.0f * scl2;
  const float q2r = sq2[r];
  float ps = 0.f;
#pragma unroll
  for (int j = 0; j < 16; ++j) {
#pragma unroll
    for (int k = 0; k < 4; ++k) {
      const float q2c = sq2[half * 64 + j * 4 + k];
      const float e = EXP2F(fmaf(v[j][k], c2, -(q2r + q2c) * scl2));
      v[j][k] = e;
      ps += e;
    }
  }
  ps += __shfl_xor(ps, 1);
  const float inv = 1.f / ps;
  uint4* Ao = (uint4*)(Aout + (size_t)bc * 16384 + (size_t)r * 128 + half * 64);
#pragma unroll
  for (int j = 0; j < 8; ++j) {
    uint4 w;
    w.x = pk2b(v[2 * j][0] * inv, v[2 * j][1] * inv);
    w.y = pk2b(v[2 * j][2] * inv, v[2 * j][3] * inv);
    w.z = pk2b(v[2 * j + 1][0] * inv, v[2 * j + 1][1] * inv);
    w.w = pk2b(v[2 * j + 1][2] * inv, v[2 * j + 1][3] * inv);
    Ao[j] = w;
  }
}

// ---------- channel PV: out[b,n,c*128+d] = sum_d' vc[b,n,c*128+d'] * A[d][d'] ----------
__global__ __launch_bounds__(256) void k_chan_pv(const u16* __restrict__ vc,
                                                 const u16* __restrict__ Ac,
                                                 u16* __restrict__ outp) {
  __shared__ u16 sm[16384];
  const int bc = blockIdx.y, b = bc >> 3, c = bc & 7;
  const int m0 = blockIdx.x * 128;
  f32x4 acc[4][4];
#pragma unroll
  for (int i = 0; i < 4; ++i)
#pragma unroll
    for (int j = 0; j < 4; ++j) acc[i][j] = (f32x4){0.f, 0.f, 0.f, 0.f};
  gemm_core_bk64(vc + ((size_t)b * 1024 + m0) * 1024 + c * 128, Ac + (size_t)bc * 16384,
                 1024, 128, 128, sm, acc);
  const int tid = threadIdx.x, wave = tid >> 6;
  const int wr = wave >> 1, wc = wave & 1;
  const int lc = tid & 15, quad = (tid & 63) >> 4;
#pragma unroll
  for (int i = 0; i < 4; ++i)
#pragma unroll
    for (int j = 0; j < 4; ++j)
#pragma unroll
      for (int r = 0; r < 4; ++r)
        outp[((size_t)(b * 1024 + m0 + wr * 64 + i * 16 + quad * 4 + r)) * 1024 + c * 128 +
             wc * 64 + j * 16 + lc] = f2b(acc[i][j][r]);
}

extern "C" void kernel_launch(void* const* d_in, const int* in_sizes, int n_in,
                              void* d_out, int out_size, void* d_ws, size_t ws_size,
                              hipStream_t stream) {
  (void)in_sizes; (void)n_in; (void)out_size; (void)ws_size;
  const float* x = (const float*)d_in[0];
  const float* tau_t = (const float*)d_in[4];
  const float* tau_c = (const float*)d_in[8];
  const float* ln1w = (const float*)d_in[9];
  const float* ln1b = (const float*)d_in[10];
  const float* ln2w = (const float*)d_in[11];
  const float* ln2b = (const float*)d_in[12];
  const float* g1 = (const float*)d_in[13];
  const float* g2 = (const float*)d_in[14];
  float* out = (float*)d_out;

  // workspace carve-up
  char* p = (char*)d_ws;
  u16* wb[6];
  for (int i = 0; i < 6; ++i) wb[i] = (u16*)(p + (size_t)i * (2u << 20));
  u16* bufA = (u16*)(p + (size_t)12 * (1u << 20));       // 16 MB
  u16* bufQ = bufA + (size_t)8 * 1024 * 1024;            // 16 MB
  u16* bufV = bufQ + (size_t)8 * 1024 * 1024;            // 16 MB
  float* q2b = (float*)(bufV + (size_t)8 * 1024 * 1024); // 512 KB
  u16* Ac = (u16*)(q2b + 131072 + 8192);                 // 2 MB

  W6 w6;
  const int widx[6] = {1, 2, 3, 5, 6, 7};  // Wqk_t, Wv_t, Wo_t, Wqk_c, Wv_c, Wo_c
  for (int i = 0; i < 6; ++i) { w6.src[i] = (const float*)d_in[widx[i]]; w6.dst[i] = wb[i]; }
  k_wtrans6<<<dim3(16, 16, 6), 256, 0, stream>>>(w6);

  // ---- token diffusion ----
  k_ln<<<8192, 256, 0, stream>>>(x, ln1w, ln1b, bufA);                           // y1 (bf16)
  k_gemm_nt2<<<dim3(64, 8), 256, 0, stream>>>(bufA, wb[0], wb[1], bufQ, bufV, q2b, tau_t);
  k_attn<<<1024, 256, 0, stream>>>(bufQ, bufV, q2b, tau_t, bufA);                // attn_out bf16
  k_gemm_res<<<dim3(64, 8), 256, 0, stream>>>(bufA, wb[2], x, g1, out);          // x1 = x + Wo*g1

  // ---- channel diffusion ----
  k_ln<<<8192, 256, 0, stream>>>(out, ln2w, ln2b, bufQ);                         // y2 (bf16)
  k_gemm_nt2<<<dim3(64, 8), 256, 0, stream>>>(bufQ, wb[4], wb[3], bufA, bufV, nullptr, tau_c);
  // y2 (bufQ) and token q2 (q2b) are dead now: reuse as split-K scratch.
  float* pG = (float*)bufQ;   // 64*4*16384 f32 = 16 MB (exactly bufQ)
  float* pDiag = q2b;         // 64*4*128 f32 = 128 KB
  k_chan_gram<<<dim3(4, 64), 256, 0, stream>>>(bufV, pG, pDiag);                 // partial Grams
  k_chan_sm<<<64, 256, 0, stream>>>(pG, pDiag, tau_c, Ac);                       // reduce+softmax
  k_chan_pv<<<dim3(8, 64), 256, 0, stream>>>(bufA, Ac, bufQ);                    // chan attn out bf16
  k_gemm_res<<<dim3(64, 8), 256, 0, stream>>>(bufQ, wb[5], out, g2, out);        // out = x1 + Wo*g2
}